// Round 5
// baseline (481.232 us; speedup 1.0000x reference)
//
#include <hip/hip_runtime.h>
#include <hip/hip_bf16.h>

// ---------------- helpers ----------------
typedef __attribute__((ext_vector_type(8))) short bf16x8;
typedef __attribute__((ext_vector_type(4))) float f32x4;
typedef __attribute__((ext_vector_type(2))) float f32x2;

__device__ __forceinline__ unsigned short f2bf(float f) {
    __hip_bfloat16 h = __float2bfloat16(f);   // round-to-nearest-even
    return __builtin_bit_cast(unsigned short, h);
}
// unpack packed bf16 pair -> f32x2 {lo, hi}
__device__ __forceinline__ f32x2 up2(unsigned int u) {
    f32x2 r;
    r.x = __builtin_bit_cast(float, u << 16);
    r.y = __builtin_bit_cast(float, u & 0xffff0000u);
    return r;
}
__device__ __forceinline__ unsigned int packbf(float lo, float hi) {
    return (unsigned int)f2bf(lo) | ((unsigned int)f2bf(hi) << 16);
}

// ---------------- CSR build ----------------
__global__ void k_hist(const int* __restrict__ dst, int* __restrict__ counts,
                       int* __restrict__ rank, int E) {
    int e = blockIdx.x * blockDim.x + threadIdx.x;
    if (e < E) rank[e] = atomicAdd(&counts[dst[e]], 1);
}

__global__ void k_psum(const int* __restrict__ counts, int* __restrict__ part, int NN) {
    __shared__ int s[256];
    int t = threadIdx.x;
    int i = blockIdx.x * 256 + t;
    s[t] = (i < NN) ? counts[i] : 0;
    __syncthreads();
    for (int off = 128; off > 0; off >>= 1) {
        if (t < off) s[t] += s[t + off];
        __syncthreads();
    }
    if (t == 0) part[blockIdx.x] = s[0];
}

__global__ void k_scatter_rs(const int* __restrict__ counts, const int* __restrict__ part,
                             int* __restrict__ row_start, int NN, int E) {
    __shared__ int s[256];
    __shared__ int q[256];
    int t = threadIdx.x;
    int b = blockIdx.x;
    q[t] = (t < b) ? part[t] : 0;
    __syncthreads();
    for (int off = 128; off > 0; off >>= 1) {
        if (t < off) q[t] += q[t + off];
        __syncthreads();
    }
    int boff = q[0];
    __syncthreads();
    int i = b * 256 + t;
    int v = (i < NN) ? counts[i] : 0;
    s[t] = v; __syncthreads();
    for (int off = 1; off < 256; off <<= 1) {
        int u = (t >= off) ? s[t - off] : 0;
        __syncthreads();
        s[t] += u;
        __syncthreads();
    }
    int ex = s[t] - v + boff;
    if (i < NN) row_start[i] = ex;
    if (i == NN - 1) row_start[NN] = E;
}

__global__ void k_fill(const int* __restrict__ src, const int* __restrict__ dst,
                       const int* __restrict__ rank, const int* __restrict__ row_start,
                       unsigned short* __restrict__ csrc, int E) {
    int e = blockIdx.x * blockDim.x + threadIdx.x;
    if (e < E) csrc[row_start[dst[e]] + rank[e]] = (unsigned short)src[e];
}

// ---------------- fused dtype conversions (one launch) ----------------
// xb is written in XCD-slab layout: slab s (16 feats = 32 B) holds all
// nodes' bytes [s*32, s*32+32) contiguously -> 1.6 MB per slab, so the
// agg gathers for slice s are resident in one XCD's 4-MiB L2.
__global__ void k_cvt_all(const float4* __restrict__ x4, ushort4* __restrict__ xb4, int n4x, int nbx,
                          const float* __restrict__ W1, unsigned short* __restrict__ w1t,
                          const float* __restrict__ W2, unsigned short* __restrict__ w2t,
                          const float* __restrict__ W3, unsigned short* __restrict__ w3t) {
    int b = blockIdx.x;
    if (b < nbx) {
        int i = b * 256 + threadIdx.x;
        if (i < n4x) {
            int Mloc = n4x >> 5;              // 32 float4 chunks per node (128 feats)
            float4 v = x4[i];
            ushort4 o; o.x = f2bf(v.x); o.y = f2bf(v.y); o.z = f2bf(v.z); o.w = f2bf(v.w);
            int node = i >> 5, dw = i & 31;
            // slab = dw>>2 (4 float4 groups = 16 feats), within-slab ushort4 = dw&3
            xb4[((size_t)(dw >> 2) * Mloc + node) * 4 + (dw & 3)] = o;
        }
        return;
    }
    b -= nbx;
    const float* w; unsigned short* wt; int K;
    if (b < 128)      { w = W1; wt = w1t; K = 128; }
    else if (b < 384) { w = W2; wt = w2t; K = 256; b -= 128; }
    else              { w = W3; wt = w3t; K = 256; b -= 384; }
    int i = b * 256 + threadIdx.x;   // i < K*256
    int k = i >> 8, n = i & 255;
    wt[n * K + k] = f2bf(w[i]);
}

// ---------------- XCD-sliced bf16 CSR aggregation (layer 1) ----------------
// Rounds 1/2/4 converged at ~45 us with FETCH 88.8 MB (~30 G 64B-lines/s):
// the wall is the random-line L2-miss service rate, not latency hiding.
// Fix: shard FEATURES across XCDs. slice = blockIdx.x & 7 rides the
// round-robin workgroup->XCD dispatch; slice's gather table is a 1.6 MB
// slab -> L2-resident. Lane = (edge-stream ep = lane>>3, feat-dword
// fq = lane&7): 8 edges x 32 B per round, all 64 lanes useful, no shfl
// in the index path (broadcast csrc loads), next index prefetched.
__global__ __launch_bounds__(256)
void k_agg(const unsigned short* __restrict__ xb, const int* __restrict__ rs,
           const unsigned short* __restrict__ csrc, unsigned short* __restrict__ out,
           int NN, int E) {
    int bid = blockIdx.x;
    int slice = bid & 7;
    int ngrp = bid >> 3;
    int tid = threadIdx.x;
    int lane = tid & 63;
    int ep = lane >> 3, fq = lane & 7;
    const unsigned char* xs = (const unsigned char*)xb + (size_t)slice * ((size_t)NN * 32);
    int Em1 = E - 1;
    int n0 = (ngrp * 4 + (tid >> 6)) * 8;
#pragma unroll 1
    for (int ni = 0; ni < 8; ++ni) {
        int node = n0 + ni;
        if (node >= NN) return;
        int k0 = rs[node];
        int cnt = rs[node + 1] - k0;
        f32x2 acc = {0.f, 0.f};
        int rounds = (cnt + 7) >> 3;
        int e = ep;
        int row = (int)csrc[min(k0 + e, Em1)];
        for (int r = 0; r < rounds; ++r) {
            unsigned v = *(const unsigned*)(xs + ((size_t)row << 5) + (fq << 2));
            int en = e + 8;
            int rn = (int)csrc[min(k0 + en, Em1)];
            v = (e < cnt) ? v : 0u;
            acc += up2(v);
            e = en; row = rn;
        }
#pragma unroll
        for (int off = 8; off <= 32; off <<= 1) {
            acc.x += __shfl_xor(acc.x, off, 64);
            acc.y += __shfl_xor(acc.y, off, 64);
        }
        if (ep == 0)
            *(unsigned*)(out + (size_t)node * 128 + slice * 16 + fq * 2) = packbf(acc.x, acc.y);
    }
}

// ---------------- XCD-sliced int8 CSR aggregation (layers 2&3) ----------------
// h8 is stored in slab layout by the GEMM quant epilogue. Masked edges
// contribute 0 via a zeroed scale; gather addresses are always legal
// (clamped csrc index reads a real node id).
__global__ __launch_bounds__(256)
void k_agg8(const unsigned char* __restrict__ h8, const float* __restrict__ scales,
            const int* __restrict__ rs, const unsigned short* __restrict__ csrc,
            unsigned short* __restrict__ out, int NN, int E) {
    int bid = blockIdx.x;
    int slice = bid & 7;
    int ngrp = bid >> 3;
    int tid = threadIdx.x;
    int lane = tid & 63;
    int ep = lane >> 3, fq = lane & 7;
    int q = slice >> 1;                      // 64-col scale quarter
    const unsigned char* hs = h8 + (size_t)slice * ((size_t)NN * 32);
    const float* scq = scales + q;
    int Em1 = E - 1;
    int n0 = (ngrp * 4 + (tid >> 6)) * 8;
#pragma unroll 1
    for (int ni = 0; ni < 8; ++ni) {
        int node = n0 + ni;
        if (node >= NN) return;
        int k0 = rs[node];
        int cnt = rs[node + 1] - k0;
        f32x2 a0 = {0.f, 0.f}, a1 = {0.f, 0.f};
        int rounds = (cnt + 7) >> 3;
        int e = ep;
        int row = (int)csrc[min(k0 + e, Em1)];
        for (int r = 0; r < rounds; ++r) {
            unsigned v = *(const unsigned*)(hs + ((size_t)row << 5) + (fq << 2));
            float s0 = scq[row << 2];
            int en = e + 8;
            int rn = (int)csrc[min(k0 + en, Em1)];
            float sc = (e < cnt) ? s0 : 0.f;
            f32x2 s2 = {sc, sc};
            a0 += (f32x2){(float)(v & 0xff), (float)((v >> 8) & 0xff)} * s2;
            a1 += (f32x2){(float)((v >> 16) & 0xff), (float)(v >> 24)} * s2;
            e = en; row = rn;
        }
#pragma unroll
        for (int off = 8; off <= 32; off <<= 1) {
            a0.x += __shfl_xor(a0.x, off, 64);
            a0.y += __shfl_xor(a0.y, off, 64);
            a1.x += __shfl_xor(a1.x, off, 64);
            a1.y += __shfl_xor(a1.y, off, 64);
        }
        if (ep == 0) {
            uint2 o; o.x = packbf(a0.x, a0.y); o.y = packbf(a1.x, a1.y);
            *(uint2*)(out + (size_t)node * 256 + slice * 32 + fq * 4) = o;
        }
    }
}

// ---------------- MFMA GEMM: C = relu(A @ W + b) ----------------
// Stage-B-once design (round 2). K <= 256 so a block's 64-col B-slab
// (16-32 KB) is staged in LDS ONCE, one __syncthreads, then a fully-
// unrolled barrier-free K-loop with A direct from global and B from LDS.
// QUANT epilogue now writes h8 in XCD-slab layout (slab = n>>5, 32 B per
// node per slab) to make the next agg8's gathers per-XCD L2-resident.
template <bool QUANT, int K>
__global__ __launch_bounds__(256, 4)
void k_gemm(const unsigned short* __restrict__ A, const unsigned short* __restrict__ Bt,
            const float* __restrict__ bias, void* __restrict__ Cout,
            float* __restrict__ scales, int M) {
    constexpr int LDB = K + 8;
    __shared__ unsigned short Bs[64 * LDB];
    int tid = threadIdx.x;
    int lane = tid & 63, quad = lane >> 4, l16 = lane & 15;
    int w = tid >> 6;
    int cbase = blockIdx.x * 64;
    int mrow0 = blockIdx.y * 256 + w * 64;

    // stage the block's B slab (64 cols x K) once
    constexpr int CH = K / 8;            // uint4 chunks per slab row
    constexpr int NCH = 64 * CH;
#pragma unroll
    for (int ch = tid; ch < NCH; ch += 256) {
        int c = ch / CH;
        int kk = (ch % CH) * 8;
        uint4 v = *((const uint4*)(Bt + (size_t)(cbase + c) * K + kk));
        *((uint4*)&Bs[c * LDB + kk]) = v;
    }
    __syncthreads();

    // A fragment base pointers (rows clamped; tail rows never stored)
    const unsigned short* Ap[4];
#pragma unroll
    for (int mt = 0; mt < 4; ++mt) {
        int r = mrow0 + mt * 16 + l16;
        if (r >= M) r = M - 1;
        Ap[mt] = A + (size_t)r * K + quad * 8;
    }

    f32x4 acc[4][4];
#pragma unroll
    for (int i = 0; i < 4; ++i)
#pragma unroll
        for (int j = 0; j < 4; ++j) acc[i][j] = (f32x4){0.f, 0.f, 0.f, 0.f};

#pragma unroll
    for (int s = 0; s < K / 32; ++s) {
        bf16x8 af[4], bfr[4];
#pragma unroll
        for (int mt = 0; mt < 4; ++mt) af[mt] = *((const bf16x8*)(Ap[mt] + s * 32));
#pragma unroll
        for (int nt = 0; nt < 4; ++nt)
            bfr[nt] = *((const bf16x8*)&Bs[(nt * 16 + l16) * LDB + s * 32 + quad * 8]);
#pragma unroll
        for (int mt = 0; mt < 4; ++mt)
#pragma unroll
            for (int nt = 0; nt < 4; ++nt)
                acc[mt][nt] = __builtin_amdgcn_mfma_f32_16x16x32_bf16(af[mt], bfr[nt], acc[mt][nt], 0, 0, 0);
    }

    // bias + relu in-place.  C/D layout: col = lane&15, row = quad*4 + reg
    float bv[4];
#pragma unroll
    for (int nt = 0; nt < 4; ++nt) bv[nt] = bias[cbase + nt * 16 + l16];
#pragma unroll
    for (int mt = 0; mt < 4; ++mt)
#pragma unroll
        for (int nt = 0; nt < 4; ++nt)
#pragma unroll
            for (int r = 0; r < 4; ++r) {
                float v = acc[mt][nt][r] + bv[nt];
                acc[mt][nt][r] = v > 0.f ? v : 0.f;
            }

    if constexpr (QUANT) {
        unsigned char* h8 = (unsigned char*)Cout;
        size_t slab = (size_t)M * 32;
        int qid = blockIdx.x;            // 64-col quarter id
#pragma unroll
        for (int mt = 0; mt < 4; ++mt) {
#pragma unroll
            for (int r = 0; r < 4; ++r) {
                float mx = fmaxf(fmaxf(acc[mt][0][r], acc[mt][1][r]),
                                 fmaxf(acc[mt][2][r], acc[mt][3][r]));
#pragma unroll
                for (int off = 1; off < 16; off <<= 1)
                    mx = fmaxf(mx, __shfl_xor(mx, off, 64));
                float inv = mx > 0.f ? 255.0f / mx : 0.0f;
                int m = mrow0 + mt * 16 + quad * 4 + r;
                if (m < M) {
#pragma unroll
                    for (int nt = 0; nt < 4; ++nt) {
                        int n = cbase + nt * 16 + l16;
                        unsigned u = (unsigned)(acc[mt][nt][r] * inv + 0.5f);
                        h8[(size_t)(n >> 5) * slab + (size_t)m * 32 + (n & 31)] = (unsigned char)u;
                    }
                    if (l16 == 0) scales[(size_t)m * 4 + qid] = mx * (1.0f / 255.0f);
                }
            }
        }
    } else {
        float* C = (float*)Cout;
#pragma unroll
        for (int mt = 0; mt < 4; ++mt)
#pragma unroll
            for (int nt = 0; nt < 4; ++nt) {
                int n = cbase + nt * 16 + l16;
#pragma unroll
                for (int r = 0; r < 4; ++r) {
                    int m = mrow0 + mt * 16 + quad * 4 + r;
                    if (m < M) C[(size_t)m * 256 + n] = acc[mt][nt][r];
                }
            }
    }
}

// ---------------- host ----------------
static inline size_t alignup(size_t x) { return (x + 255) & ~(size_t)255; }

extern "C" void kernel_launch(void* const* d_in, const int* in_sizes, int n_in,
                              void* d_out, int out_size, void* d_ws, size_t ws_size,
                              hipStream_t stream) {
    const float* x  = (const float*)d_in[0];
    const int* ei   = (const int*)d_in[1];    // int32 on device (harness converts)
    const float* W1 = (const float*)d_in[2];
    const float* b1 = (const float*)d_in[3];
    const float* W2 = (const float*)d_in[4];
    const float* b2 = (const float*)d_in[5];
    const float* W3 = (const float*)d_in[6];
    const float* b3 = (const float*)d_in[7];

    const int M = in_sizes[0] / 128;      // 50000 nodes
    const int E = in_sizes[1] / 2;        // 800000 edges
    const int* srcp = ei;
    const int* dstp = ei + E;
    const int nscan = (M + 255) / 256;

    // workspace carve-up (~45 MB). h8 (12.8 MB) + scales (0.8 MB) live in
    // d_out: both dead before gemm3 overwrites d_out with fp32.
    char* p = (char*)d_ws;
    size_t off = 0;
    auto carve = [&](size_t bytes) { void* r = p + off; off += alignup(bytes); return r; };
    int* counts    = (int*)carve((size_t)M * 4);
    int* row_start = (int*)carve((size_t)(M + 1) * 4);
    int* part      = (int*)carve((size_t)256 * 4);
    int* rank      = (int*)carve((size_t)E * 4);
    unsigned short* csrc = (unsigned short*)carve((size_t)E * 2);
    unsigned short* w1t = (unsigned short*)carve((size_t)128 * 256 * 2);
    unsigned short* w2t = (unsigned short*)carve((size_t)256 * 256 * 2);
    unsigned short* w3t = (unsigned short*)carve((size_t)256 * 256 * 2);
    unsigned short* xb  = (unsigned short*)carve((size_t)M * 128 * 2);
    unsigned short* ab  = (unsigned short*)carve((size_t)M * 256 * 2);  // a1/a2/a3 (bf16)
    unsigned char* h8   = (unsigned char*)d_out;                         // h1/h2 int8 (slab layout)
    float* scales       = (float*)((char*)d_out + (size_t)M * 256);      // 4 per node

    // 1) CSR build (rank trick: no atomics in fill)
    hipMemsetAsync(counts, 0, (size_t)M * 4, stream);
    k_hist<<<(E + 255) / 256, 256, 0, stream>>>(dstp, counts, rank, E);
    k_psum<<<nscan, 256, 0, stream>>>(counts, part, M);
    k_scatter_rs<<<nscan, 256, 0, stream>>>(counts, part, row_start, M, E);
    k_fill<<<(E + 255) / 256, 256, 0, stream>>>(srcp, dstp, rank, row_start, csrc, E);

    // 2) conversions (single launch)
    int n4x = M * 128 / 4;
    int nbx = (n4x + 255) / 256;
    k_cvt_all<<<nbx + 128 + 256 + 256, 256, 0, stream>>>(
        (const float4*)x, (ushort4*)xb, n4x, nbx, W1, w1t, W2, w2t, W3, w3t);

    dim3 ggrid(4, (M + 255) / 256);
    int aggblocks = ((M + 31) / 32) * 8;   // 32 nodes per block x 8 XCD slices

    // layer 1: a1 = agg(x); h1 = quant8(relu(a1 @ W1 + b1))
    k_agg<<<aggblocks, 256, 0, stream>>>(xb, row_start, csrc, ab, M, E);
    k_gemm<true, 128><<<ggrid, 256, 0, stream>>>(ab, w1t, b1, h8, scales, M);

    // layer 2: a2 = agg8(h1); h2 = quant8(relu(a2 @ W2 + b2))
    k_agg8<<<aggblocks, 256, 0, stream>>>(h8, scales, row_start, csrc, ab, M, E);
    k_gemm<true, 256><<<ggrid, 256, 0, stream>>>(ab, w2t, b2, h8, scales, M);

    // layer 3: a3 = agg8(h2); out = relu(a3 @ W3 + b3)
    k_agg8<<<aggblocks, 256, 0, stream>>>(h8, scales, row_start, csrc, ab, M, E);
    k_gemm<false, 256><<<ggrid, 256, 0, stream>>>(ab, w3t, b3, d_out, nullptr, M);
}

// Round 6
// 336.482 us; speedup vs baseline: 1.4302x; 1.4302x over previous
//
#include <hip/hip_runtime.h>
#include <hip/hip_bf16.h>

// ---------------- helpers ----------------
typedef __attribute__((ext_vector_type(8))) short bf16x8;
typedef __attribute__((ext_vector_type(4))) float f32x4;
typedef __attribute__((ext_vector_type(2))) float f32x2;

__device__ __forceinline__ unsigned short f2bf(float f) {
    __hip_bfloat16 h = __float2bfloat16(f);   // round-to-nearest-even
    return __builtin_bit_cast(unsigned short, h);
}
// unpack packed bf16 pair -> f32x2 {lo, hi}
__device__ __forceinline__ f32x2 up2(unsigned int u) {
    f32x2 r;
    r.x = __builtin_bit_cast(float, u << 16);
    r.y = __builtin_bit_cast(float, u & 0xffff0000u);
    return r;
}
__device__ __forceinline__ unsigned int packbf(float lo, float hi) {
    return (unsigned int)f2bf(lo) | ((unsigned int)f2bf(hi) << 16);
}

// ---------------- CSR build ----------------
__global__ void k_hist(const int* __restrict__ dst, int* __restrict__ counts,
                       int* __restrict__ rank, int E) {
    int e = blockIdx.x * blockDim.x + threadIdx.x;
    if (e < E) rank[e] = atomicAdd(&counts[dst[e]], 1);
}

__global__ void k_psum(const int* __restrict__ counts, int* __restrict__ part, int NN) {
    __shared__ int s[256];
    int t = threadIdx.x;
    int i = blockIdx.x * 256 + t;
    s[t] = (i < NN) ? counts[i] : 0;
    __syncthreads();
    for (int off = 128; off > 0; off >>= 1) {
        if (t < off) s[t] += s[t + off];
        __syncthreads();
    }
    if (t == 0) part[blockIdx.x] = s[0];
}

__global__ void k_scatter_rs(const int* __restrict__ counts, const int* __restrict__ part,
                             int* __restrict__ row_start, int NN, int E) {
    __shared__ int s[256];
    __shared__ int q[256];
    int t = threadIdx.x;
    int b = blockIdx.x;
    q[t] = (t < b) ? part[t] : 0;
    __syncthreads();
    for (int off = 128; off > 0; off >>= 1) {
        if (t < off) q[t] += q[t + off];
        __syncthreads();
    }
    int boff = q[0];
    __syncthreads();
    int i = b * 256 + t;
    int v = (i < NN) ? counts[i] : 0;
    s[t] = v; __syncthreads();
    for (int off = 1; off < 256; off <<= 1) {
        int u = (t >= off) ? s[t - off] : 0;
        __syncthreads();
        s[t] += u;
        __syncthreads();
    }
    int ex = s[t] - v + boff;
    if (i < NN) row_start[i] = ex;
    if (i == NN - 1) row_start[NN] = E;
}

__global__ void k_fill(const int* __restrict__ src, const int* __restrict__ dst,
                       const int* __restrict__ rank, const int* __restrict__ row_start,
                       unsigned short* __restrict__ csrc, int E) {
    int e = blockIdx.x * blockDim.x + threadIdx.x;
    if (e < E) csrc[row_start[dst[e]] + rank[e]] = (unsigned short)src[e];
}

// ---------------- fused dtype conversions (one launch) ----------------
__global__ void k_cvt_all(const float4* __restrict__ x4, ushort4* __restrict__ xb4, int n4x, int nbx,
                          const float* __restrict__ W1, unsigned short* __restrict__ w1t,
                          const float* __restrict__ W2, unsigned short* __restrict__ w2t,
                          const float* __restrict__ W3, unsigned short* __restrict__ w3t) {
    int b = blockIdx.x;
    if (b < nbx) {
        int i = b * 256 + threadIdx.x;
        if (i < n4x) {
            float4 v = x4[i];
            ushort4 o; o.x = f2bf(v.x); o.y = f2bf(v.y); o.z = f2bf(v.z); o.w = f2bf(v.w);
            xb4[i] = o;
        }
        return;
    }
    b -= nbx;
    const float* w; unsigned short* wt; int K;
    if (b < 128)      { w = W1; wt = w1t; K = 128; }
    else if (b < 384) { w = W2; wt = w2t; K = 256; b -= 128; }
    else              { w = W3; wt = w3t; K = 256; b -= 384; }
    int i = b * 256 + threadIdx.x;   // i < K*256
    int k = i >> 8, n = i & 255;
    wt[n * K + k] = f2bf(w[i]);
}

// ---------------- bf16 CSR aggregation (layer 1, x table, F=128) ----------------
// Round-5 null: killing L2 misses (FETCH 88.8 -> 16.5 MB) made agg SLOWER
// -> the ~45 us plateau is not miss-service-bound. Round-4 counters (VALU
// 60%, HBM 31%) + inst count (~12 wave-VALU/edge in the half-wave unpack
// + shfl reduction epilogue) say it is VALU/issue-heavy. Fix: full-wave-
// per-edge layout. Lane l owns bytes [4l,4l+4) of the row: per edge, ONE
// 4-B load/lane (same 4 lines/row), ~4 VALU, accumulators lane-private
// for fixed columns -> NO cross-lane reduction, fully-coalesced output.
// Ping-pong 2x4-edge buffers keeps 8 edges in flight; csrc/scale reads
// stay 1x (round-5's 8x redundancy avoided).
__global__ __launch_bounds__(256)
void k_agg(const unsigned short* __restrict__ h, const int* __restrict__ rs,
           const unsigned short* __restrict__ csrc, unsigned short* __restrict__ out, int NN) {
    int gid = blockIdx.x * blockDim.x + threadIdx.x;
    int node = gid >> 6;
    if (node >= NN) return;
    int lane = threadIdx.x & 63;
    int k0 = rs[node], k1 = rs[node + 1];
    int cnt = k1 - k0;
    const unsigned char* hb = (const unsigned char*)h;

    f32x2 acc = {0.f, 0.f};

    for (int base = 0; base < cnt; base += 64) {
        int nk = min(cnt - base, 64);
        int myidx = (lane < nk) ? (int)csrc[k0 + base + lane] : 0;
        int nb = (nk + 3) >> 2;

        auto issue = [&](int j, unsigned (&v)[4]) {
#pragma unroll
            for (int b = 0; b < 4; ++b) {
                int row = __shfl(myidx, j + b, 64);
                v[b] = *(const unsigned*)(hb + (size_t)row * 256 + lane * 4);
            }
        };
        auto consume = [&](int j, unsigned (&v)[4]) {
#pragma unroll
            for (int b = 0; b < 4; ++b) {
                unsigned x = (j + b < nk) ? v[b] : 0u;
                acc += up2(x);
            }
        };

        unsigned vA[4], vB[4];
        issue(0, vA);
        for (int b = 1; b < nb; ++b) {
            if (b & 1) { issue(b * 4, vB); consume((b - 1) * 4, vA); }
            else       { issue(b * 4, vA); consume((b - 1) * 4, vB); }
        }
        if (nb & 1) consume((nb - 1) * 4, vA);
        else        consume((nb - 1) * 4, vB);
    }

    // lane owns feats {2*lane, 2*lane+1} -> coalesced 4-B store per lane
    *(unsigned*)((unsigned char*)out + (size_t)node * 256 + lane * 4) = packbf(acc.x, acc.y);
}

// ---------------- int8 CSR aggregation (layers 2&3) ----------------
// Full-wave-per-edge: lane l owns bytes [4l,4l+4) (feats 4l..4l+3) of the
// 256-B row, quarter q = lane>>4 selects the per-(row,64-col) scale.
// Per edge: 1 payload load + 1 broadcast scale load + 1 shfl + ~7 VALU
// (4 cvt + 2 pk_fma + mask). No reduction epilogue; uint2 coalesced out.
// Masked edge slots (uniform per wave) contribute 0 via zeroed scale;
// their gather address is a real row (myidx pads with 0) -> always legal.
__global__ __launch_bounds__(256)
void k_agg8(const unsigned char* __restrict__ h8, const float* __restrict__ scales,
            const int* __restrict__ rs, const unsigned short* __restrict__ csrc,
            unsigned short* __restrict__ out, int NN) {
    int gid = blockIdx.x * blockDim.x + threadIdx.x;
    int node = gid >> 6;
    if (node >= NN) return;
    int lane = threadIdx.x & 63;
    int q = lane >> 4;                 // 64-col quarter of this lane's 4 feats
    int k0 = rs[node], k1 = rs[node + 1];
    int cnt = k1 - k0;

    f32x2 a0 = {0.f, 0.f}, a1 = {0.f, 0.f};

    for (int base = 0; base < cnt; base += 64) {
        int nk = min(cnt - base, 64);
        int myidx = (lane < nk) ? (int)csrc[k0 + base + lane] : 0;
        int nb = (nk + 3) >> 2;

        auto issue = [&](int j, unsigned (&v)[4], float (&s)[4]) {
#pragma unroll
            for (int b = 0; b < 4; ++b) {
                int row = __shfl(myidx, j + b, 64);
                v[b] = *(const unsigned*)(h8 + (size_t)row * 256 + lane * 4);
                s[b] = scales[row * 4 + q];
            }
        };
        auto consume = [&](int j, unsigned (&v)[4], float (&s)[4]) {
#pragma unroll
            for (int b = 0; b < 4; ++b) {
                float sc = (j + b < nk) ? s[b] : 0.f;
                f32x2 s2 = {sc, sc};
                unsigned x = v[b];
                a0 += (f32x2){(float)(x & 0xff), (float)((x >> 8) & 0xff)} * s2;
                a1 += (f32x2){(float)((x >> 16) & 0xff), (float)(x >> 24)} * s2;
            }
        };

        unsigned vA[4], vB[4]; float sA[4], sB[4];
        issue(0, vA, sA);
        for (int b = 1; b < nb; ++b) {
            if (b & 1) { issue(b * 4, vB, sB); consume((b - 1) * 4, vA, sA); }
            else       { issue(b * 4, vA, sA); consume((b - 1) * 4, vB, sB); }
        }
        if (nb & 1) consume((nb - 1) * 4, vA, sA);
        else        consume((nb - 1) * 4, vB, sB);
    }

    // lane owns feats [4*lane, 4*lane+4) -> coalesced 8-B store per lane
    uint2 o; o.x = packbf(a0.x, a0.y); o.y = packbf(a1.x, a1.y);
    *(uint2*)((unsigned char*)out + (size_t)node * 512 + lane * 8) = o;
}

// ---------------- MFMA GEMM: C = relu(A @ W + b) ----------------
// Stage-B-once design (round 2/4). K <= 256 so a block's 64-col B-slab
// (16-32 KB) is staged in LDS ONCE, one __syncthreads, then a fully-
// unrolled barrier-free K-loop with A direct from global (line-perfect:
// 16 rows x 64 B per fragment load) and B from LDS (padded stride K+8).
// QUANT epilogue: row-major h8 (round-4 layout; round-5's slab scatter
// reverted) + per-(row, 64-col) fp32 scale.
template <bool QUANT, int K>
__global__ __launch_bounds__(256, 4)
void k_gemm(const unsigned short* __restrict__ A, const unsigned short* __restrict__ Bt,
            const float* __restrict__ bias, void* __restrict__ Cout,
            float* __restrict__ scales, int M) {
    constexpr int LDB = K + 8;
    __shared__ unsigned short Bs[64 * LDB];
    int tid = threadIdx.x;
    int lane = tid & 63, quad = lane >> 4, l16 = lane & 15;
    int w = tid >> 6;
    int cbase = blockIdx.x * 64;
    int mrow0 = blockIdx.y * 256 + w * 64;

    // stage the block's B slab (64 cols x K) once
    constexpr int CH = K / 8;            // uint4 chunks per slab row
    constexpr int NCH = 64 * CH;
#pragma unroll
    for (int ch = tid; ch < NCH; ch += 256) {
        int c = ch / CH;
        int kk = (ch % CH) * 8;
        uint4 v = *((const uint4*)(Bt + (size_t)(cbase + c) * K + kk));
        *((uint4*)&Bs[c * LDB + kk]) = v;
    }
    __syncthreads();

    // A fragment base pointers (rows clamped; tail rows never stored)
    const unsigned short* Ap[4];
#pragma unroll
    for (int mt = 0; mt < 4; ++mt) {
        int r = mrow0 + mt * 16 + l16;
        if (r >= M) r = M - 1;
        Ap[mt] = A + (size_t)r * K + quad * 8;
    }

    f32x4 acc[4][4];
#pragma unroll
    for (int i = 0; i < 4; ++i)
#pragma unroll
        for (int j = 0; j < 4; ++j) acc[i][j] = (f32x4){0.f, 0.f, 0.f, 0.f};

#pragma unroll
    for (int s = 0; s < K / 32; ++s) {
        bf16x8 af[4], bfr[4];
#pragma unroll
        for (int mt = 0; mt < 4; ++mt) af[mt] = *((const bf16x8*)(Ap[mt] + s * 32));
#pragma unroll
        for (int nt = 0; nt < 4; ++nt)
            bfr[nt] = *((const bf16x8*)&Bs[(nt * 16 + l16) * LDB + s * 32 + quad * 8]);
#pragma unroll
        for (int mt = 0; mt < 4; ++mt)
#pragma unroll
            for (int nt = 0; nt < 4; ++nt)
                acc[mt][nt] = __builtin_amdgcn_mfma_f32_16x16x32_bf16(af[mt], bfr[nt], acc[mt][nt], 0, 0, 0);
    }

    // bias + relu in-place.  C/D layout: col = lane&15, row = quad*4 + reg
    float bv[4];
#pragma unroll
    for (int nt = 0; nt < 4; ++nt) bv[nt] = bias[cbase + nt * 16 + l16];
#pragma unroll
    for (int mt = 0; mt < 4; ++mt)
#pragma unroll
        for (int nt = 0; nt < 4; ++nt)
#pragma unroll
            for (int r = 0; r < 4; ++r) {
                float v = acc[mt][nt][r] + bv[nt];
                acc[mt][nt][r] = v > 0.f ? v : 0.f;
            }

    if constexpr (QUANT) {
        unsigned char* h8 = (unsigned char*)Cout;
        int qid = blockIdx.x;            // 64-col quarter id
#pragma unroll
        for (int mt = 0; mt < 4; ++mt) {
#pragma unroll
            for (int r = 0; r < 4; ++r) {
                float mx = fmaxf(fmaxf(acc[mt][0][r], acc[mt][1][r]),
                                 fmaxf(acc[mt][2][r], acc[mt][3][r]));
#pragma unroll
                for (int off = 1; off < 16; off <<= 1)
                    mx = fmaxf(mx, __shfl_xor(mx, off, 64));
                float inv = mx > 0.f ? 255.0f / mx : 0.0f;
                int m = mrow0 + mt * 16 + quad * 4 + r;
                if (m < M) {
#pragma unroll
                    for (int nt = 0; nt < 4; ++nt) {
                        int n = cbase + nt * 16 + l16;
                        unsigned u = (unsigned)(acc[mt][nt][r] * inv + 0.5f);
                        h8[(size_t)m * 256 + n] = (unsigned char)u;
                    }
                    if (l16 == 0) scales[(size_t)m * 4 + qid] = mx * (1.0f / 255.0f);
                }
            }
        }
    } else {
        float* C = (float*)Cout;
#pragma unroll
        for (int mt = 0; mt < 4; ++mt)
#pragma unroll
            for (int nt = 0; nt < 4; ++nt) {
                int n = cbase + nt * 16 + l16;
#pragma unroll
                for (int r = 0; r < 4; ++r) {
                    int m = mrow0 + mt * 16 + quad * 4 + r;
                    if (m < M) C[(size_t)m * 256 + n] = acc[mt][nt][r];
                }
            }
    }
}

// ---------------- host ----------------
static inline size_t alignup(size_t x) { return (x + 255) & ~(size_t)255; }

extern "C" void kernel_launch(void* const* d_in, const int* in_sizes, int n_in,
                              void* d_out, int out_size, void* d_ws, size_t ws_size,
                              hipStream_t stream) {
    const float* x  = (const float*)d_in[0];
    const int* ei   = (const int*)d_in[1];    // int32 on device (harness converts)
    const float* W1 = (const float*)d_in[2];
    const float* b1 = (const float*)d_in[3];
    const float* W2 = (const float*)d_in[4];
    const float* b2 = (const float*)d_in[5];
    const float* W3 = (const float*)d_in[6];
    const float* b3 = (const float*)d_in[7];

    const int M = in_sizes[0] / 128;      // 50000 nodes
    const int E = in_sizes[1] / 2;        // 800000 edges
    const int* srcp = ei;
    const int* dstp = ei + E;
    const int nscan = (M + 255) / 256;

    // workspace carve-up (~45 MB). h8 (12.8 MB) + scales (0.8 MB) live in
    // d_out: both dead before gemm3 overwrites d_out with fp32.
    char* p = (char*)d_ws;
    size_t off = 0;
    auto carve = [&](size_t bytes) { void* r = p + off; off += alignup(bytes); return r; };
    int* counts    = (int*)carve((size_t)M * 4);
    int* row_start = (int*)carve((size_t)(M + 1) * 4);
    int* part      = (int*)carve((size_t)256 * 4);
    int* rank      = (int*)carve((size_t)E * 4);
    unsigned short* csrc = (unsigned short*)carve((size_t)E * 2);
    unsigned short* w1t = (unsigned short*)carve((size_t)128 * 256 * 2);
    unsigned short* w2t = (unsigned short*)carve((size_t)256 * 256 * 2);
    unsigned short* w3t = (unsigned short*)carve((size_t)256 * 256 * 2);
    unsigned short* xb  = (unsigned short*)carve((size_t)M * 128 * 2);
    unsigned short* ab  = (unsigned short*)carve((size_t)M * 256 * 2);  // a1/a2/a3 (bf16)
    unsigned char* h8   = (unsigned char*)d_out;                         // h1/h2 int8
    float* scales       = (float*)((char*)d_out + (size_t)M * 256);      // 4 per node

    // 1) CSR build (rank trick: no atomics in fill)
    hipMemsetAsync(counts, 0, (size_t)M * 4, stream);
    k_hist<<<(E + 255) / 256, 256, 0, stream>>>(dstp, counts, rank, E);
    k_psum<<<nscan, 256, 0, stream>>>(counts, part, M);
    k_scatter_rs<<<nscan, 256, 0, stream>>>(counts, part, row_start, M, E);
    k_fill<<<(E + 255) / 256, 256, 0, stream>>>(srcp, dstp, rank, row_start, csrc, E);

    // 2) conversions (single launch)
    int n4x = M * 128 / 4;
    int nbx = (n4x + 255) / 256;
    k_cvt_all<<<nbx + 128 + 256 + 256, 256, 0, stream>>>(
        (const float4*)x, (ushort4*)xb, n4x, nbx, W1, w1t, W2, w2t, W3, w3t);

    dim3 ggrid(4, (M + 255) / 256);
    int aggblocks = (M * 64 + 255) / 256;

    // layer 1: a1 = agg(x); h1 = quant8(relu(a1 @ W1 + b1))
    k_agg<<<aggblocks, 256, 0, stream>>>(xb, row_start, csrc, ab, M);
    k_gemm<true, 128><<<ggrid, 256, 0, stream>>>(ab, w1t, b1, h8, scales, M);

    // layer 2: a2 = agg8(h1); h2 = quant8(relu(a2 @ W2 + b2))
    k_agg8<<<aggblocks, 256, 0, stream>>>(h8, scales, row_start, csrc, ab, M);
    k_gemm<true, 256><<<ggrid, 256, 0, stream>>>(ab, w2t, b2, h8, scales, M);

    // layer 3: a3 = agg8(h2); out = relu(a3 @ W3 + b3)
    k_agg8<<<aggblocks, 256, 0, stream>>>(h8, scales, row_start, csrc, ab, M);
    k_gemm<false, 256><<<ggrid, 256, 0, stream>>>(ab, w3t, b3, d_out, nullptr, M);
}